// Round 4
// baseline (29392.941 us; speedup 1.0000x reference)
//
#include <hip/hip_runtime.h>

#define NTOT   262144
#define H      512
#define NSEG   64
#define TPB    256
#define NMLP   64
#define NSTRM  512
#define NBLK   (NMLP + NSTRM)        // 576 blocks, all co-resident
#define CROWS  32                    // rows per chunk
#define NCHUNK (NTOT / CROWS)        // 8192
#define ROUNDS (NCHUNK / NSTRM)      // 16
#define QV     (H / 4)               // 128 float4 per row
#define RROWS  (NSTRM * CROWS)       // 16384 rows per round

typedef float f4 __attribute__((ext_vector_type(4)));

__device__ __forceinline__ void ntstore4(f4* p, f4 v) {
    __builtin_nontemporal_store(v, p);
}
__device__ __forceinline__ int aload_acq(int* p) {
    return __hip_atomic_load(p, __ATOMIC_ACQUIRE, __HIP_MEMORY_SCOPE_AGENT);
}
__device__ __forceinline__ float afload(float* p) {
    return __hip_atomic_load(p, __ATOMIC_RELAXED, __HIP_MEMORY_SCOPE_AGENT);
}
__device__ __forceinline__ void afstore(float* p, float v) {
    __hip_atomic_store(p, v, __ATOMIC_RELAXED, __HIP_MEMORY_SCOPE_AGENT);
}

// ---------------------------------------------------------------------------
// Fused persistent kernel.
// Blocks 0..63   : MLP role — wait for segment s to complete, compute gate[s].
// Blocks 64..575 : streaming role — per round r: sum chunk (r, b) -> atomics;
//                  bump cum_done[r]; wait round r complete; gate chunk (r-1, b)
//                  (re-read is ~96 MiB of traffic after first read -> L3 hit).
// ---------------------------------------------------------------------------
__global__ __launch_bounds__(TPB, 4) void fused(
    const f4* __restrict__ hv, const int* __restrict__ bid,
    const float* __restrict__ W1, const float* __restrict__ b1,
    const float* __restrict__ W2, const float* __restrict__ b2,
    f4* __restrict__ out,
    float* seg_sum, int* counts, int* cum_done, int* gate_ready, float* gate)
{
    const int tid = threadIdx.x;
    const int blk = blockIdx.x;

    if (blk < NMLP) {
        // ================= MLP role =================
        const int s = blk;
        __shared__ float c[H];
        __shared__ float hd[H];
        for (int r = 0; r < ROUNDS; ++r) {
            if (tid == 0) {
                while (aload_acq(&cum_done[r]) < NSTRM) __builtin_amdgcn_s_sleep(8);
            }
            __syncthreads();
            bool done = (r == ROUNDS - 1);
            if (!done) done = (bid[(r + 1) * RROWS] > s);   // segment s ended in rounds <= r
            if (!done) continue;

            const float cnt = fmaxf(
                (float)__hip_atomic_load(&counts[s], __ATOMIC_RELAXED, __HIP_MEMORY_SCOPE_AGENT),
                1.0f);
            c[tid]       = afload(&seg_sum[s * H + tid])       / cnt;
            c[tid + 256] = afload(&seg_sum[s * H + tid + 256]) / cnt;
            __syncthreads();

            const int w = tid >> 6, l = tid & 63;
            for (int jb = 0; jb < H / 4; ++jb) {
                const int j = jb * 4 + w;
                const float* wr = W1 + (size_t)j * H;
                float acc = 0.f;
                #pragma unroll
                for (int m = 0; m < H / 64; ++m) acc += c[m * 64 + l] * wr[m * 64 + l];
                #pragma unroll
                for (int off = 32; off > 0; off >>= 1) acc += __shfl_xor(acc, off, 64);
                if (l == 0) hd[j] = fmaxf(acc + b1[j], 0.f);
            }
            __syncthreads();
            for (int jb = 0; jb < H / 4; ++jb) {
                const int j = jb * 4 + w;
                const float* wr = W2 + (size_t)j * H;
                float acc = 0.f;
                #pragma unroll
                for (int m = 0; m < H / 64; ++m) acc += hd[m * 64 + l] * wr[m * 64 + l];
                #pragma unroll
                for (int off = 32; off > 0; off >>= 1) acc += __shfl_xor(acc, off, 64);
                if (l == 0) afstore(&gate[s * H + j], 1.0f / (1.0f + expf(-(acc + b2[j]))));
            }
            __syncthreads();
            if (tid == 0)
                __hip_atomic_store(&gate_ready[s], 1, __ATOMIC_RELEASE, __HIP_MEMORY_SCOPE_AGENT);
            return;
        }
        return;
    }

    // ================= streaming role =================
    const int b = blk - NMLP;       // 0..511
    const int g = tid >> 7;         // row-parity group 0..1
    const int q = tid & 127;        // float4 column

    __shared__ int sbid[CROWS];
    __shared__ int gbid[CROWS];
    __shared__ f4  sred[2][QV];

    const f4* gp = (const f4*)gate;

    auto gate_phase = [&](int pr, int wr) {
        const int base = (pr * NSTRM + b) * CROWS;
        if (tid < CROWS) gbid[tid] = bid[base + tid];
        __syncthreads();
        if (tid == 0) {
            while (aload_acq(&cum_done[wr]) < NSTRM) __builtin_amdgcn_s_sleep(8);
            const int s0 = gbid[0], s1 = gbid[CROWS - 1];
            for (int s = s0; s <= s1; ++s)
                while (aload_acq(&gate_ready[s]) == 0) __builtin_amdgcn_s_sleep(2);
        }
        __syncthreads();
        const f4* p = hv  + (size_t)(base + g) * QV + q;
        f4*       o = out + (size_t)(base + g) * QV + q;
        int cur = gbid[g];
        f4 gv = gp[(size_t)cur * QV + q];
        #pragma unroll 4
        for (int i = 0; i < 16; ++i) {
            const int row = g + 2 * i;
            const int s = gbid[row];
            if (s != cur) { cur = s; gv = gp[(size_t)cur * QV + q]; }
            const f4 v = p[(size_t)(2 * i) * QV];
            ntstore4(o + (size_t)(2 * i) * QV, v * gv);
        }
    };

    for (int r = 0; r < ROUNDS; ++r) {
        // ---- sum chunk (r, b) ----
        const int base = (r * NSTRM + b) * CROWS;
        if (tid < CROWS) sbid[tid] = bid[base + tid];
        __syncthreads();

        const f4* p = hv + (size_t)(base + g) * QV + q;
        if (sbid[0] == sbid[CROWS - 1]) {
            // fast path: single-segment chunk
            f4 a0 = (f4)(0.f), a1 = (f4)(0.f), a2 = (f4)(0.f), a3 = (f4)(0.f);
            #pragma unroll
            for (int i = 0; i < 4; ++i) {
                a0 += p[(size_t)(8 * i + 0) * QV];
                a1 += p[(size_t)(8 * i + 2) * QV];
                a2 += p[(size_t)(8 * i + 4) * QV];
                a3 += p[(size_t)(8 * i + 6) * QV];
            }
            sred[g][q] = (a0 + a1) + (a2 + a3);
            __syncthreads();
            if (g == 0) {
                const int s0 = sbid[0];
                const f4 t = sred[0][q] + sred[1][q];
                float* dst = seg_sum + (size_t)s0 * H + q * 4;
                atomicAdd(dst + 0, t[0]); atomicAdd(dst + 1, t[1]);
                atomicAdd(dst + 2, t[2]); atomicAdd(dst + 3, t[3]);
                if (q == 0) atomicAdd(&counts[s0], CROWS);
            }
        } else {
            // slow path: chunk crosses a segment boundary
            f4 acc = (f4)(0.f);
            int cur = sbid[g], cnt = 0;
            for (int i = 0; i < 16; ++i) {
                const int row = g + 2 * i;
                const f4 v = p[(size_t)(2 * i) * QV];
                const int s = sbid[row];
                if (s != cur) {
                    float* dst = seg_sum + (size_t)cur * H + q * 4;
                    atomicAdd(dst + 0, acc[0]); atomicAdd(dst + 1, acc[1]);
                    atomicAdd(dst + 2, acc[2]); atomicAdd(dst + 3, acc[3]);
                    if (q == 0) atomicAdd(&counts[cur], cnt);
                    acc = (f4)(0.f); cnt = 0; cur = s;
                }
                acc += v; ++cnt;
            }
            float* dst = seg_sum + (size_t)cur * H + q * 4;
            atomicAdd(dst + 0, acc[0]); atomicAdd(dst + 1, acc[1]);
            atomicAdd(dst + 2, acc[2]); atomicAdd(dst + 3, acc[3]);
            if (q == 0) atomicAdd(&counts[cur], cnt);
        }
        __syncthreads();   // barrier drains each thread's outstanding atomics
        if (tid == 0)
            __hip_atomic_fetch_add(&cum_done[r], 1, __ATOMIC_RELEASE, __HIP_MEMORY_SCOPE_AGENT);

        // ---- gate chunk (r-1, b): needs round r fully summed ----
        if (r >= 1) gate_phase(r - 1, r);
    }
    // final chunk (round 15): cum_done[15] already confirmed at r=15 wait
    gate_phase(ROUNDS - 1, ROUNDS - 1);
}

extern "C" void kernel_launch(void* const* d_in, const int* in_sizes, int n_in,
                              void* d_out, int out_size, void* d_ws, size_t ws_size,
                              hipStream_t stream)
{
    const float* h_V      = (const float*)d_in[0];
    const int*   batch_id = (const int*)d_in[1];
    const float* W1       = (const float*)d_in[2];
    const float* b1       = (const float*)d_in[3];
    const float* W2       = (const float*)d_in[4];
    const float* b2       = (const float*)d_in[5];

    char*  ws         = (char*)d_ws;
    float* seg_sum    = (float*)ws;                 // 131072 B
    int*   counts     = (int*)(ws + 131072);        // 256 B
    int*   cum_done   = (int*)(ws + 131328);        // 64 B
    int*   gate_ready = (int*)(ws + 131392);        // 256 B
    float* gate       = (float*)(ws + 131648);      // 131072 B

    hipMemsetAsync(d_ws, 0, 131648, stream);

    fused<<<NBLK, TPB, 0, stream>>>(
        (const f4*)h_V, batch_id, W1, b1, W2, b2,
        (f4*)d_out, seg_sum, counts, cum_done, gate_ready, gate);
}

// Round 6
// 1639.877 us; speedup vs baseline: 17.9239x; 17.9239x over previous
//
#include <hip/hip_runtime.h>

#define NTOT   262144
#define H      512
#define NSEG   64
#define TPB    256
#define NMLP   64
#define NSTRM  512
#define NBLK   (NMLP + NSTRM)        // 576 blocks, all co-resident
#define CROWS  64                    // rows per chunk
#define ROUNDS (NTOT / (NSTRM * CROWS))   // 8
#define QV     (H / 4)               // 128 float4 per row
#define RROWS  (NSTRM * CROWS)       // 32768 rows per round (64 MiB)

typedef float f4 __attribute__((ext_vector_type(4)));
typedef unsigned long long u64;

__device__ __forceinline__ void ntstore4(f4* p, f4 v) {
    __builtin_nontemporal_store(v, p);
}
// ---- ALL cross-block communication via RMWs (execute at coherence point).
// Relaxed loads/stores proved NOT reliably coherent across XCDs (R5 fail);
// acquire/release fences proved catastrophically slow (R4, 75x). RMW-with-
// return is the coherent-read primitive with no cache invalidation.
__device__ __forceinline__ int ipoll(int* p) {
    return __hip_atomic_fetch_add(p, 0, __ATOMIC_RELAXED, __HIP_MEMORY_SCOPE_AGENT);
}
__device__ __forceinline__ void ibump(int* p, int v) {
    __hip_atomic_fetch_add(p, v, __ATOMIC_RELAXED, __HIP_MEMORY_SCOPE_AGENT);
}
__device__ __forceinline__ float fread_rmw(float* p) {
    return atomicAdd(p, 0.0f);               // coherent read of f32
}
__device__ __forceinline__ u64 uread_rmw(u64* p) {
    return __hip_atomic_fetch_add(p, 0ULL, __ATOMIC_RELAXED, __HIP_MEMORY_SCOPE_AGENT);
}

// ---------------------------------------------------------------------------
// Fused persistent kernel, round-pipelined for L3 reuse (verified R4:
// FETCH = 592 MB = single h_V pass).
// Blocks 0..63   : MLP role (segment s = blk).
// Blocks 64..575 : streaming role: round r: sum chunk (r,b) -> atomicAdd;
//                  bump cum_done[r]; gate chunk (r-1,b) while L3-resident.
// ---------------------------------------------------------------------------
__global__ __launch_bounds__(TPB, 4) void fused(
    const f4* __restrict__ hv, const int* __restrict__ bid,
    const float* __restrict__ W1, const float* __restrict__ b1,
    const float* __restrict__ W2, const float* __restrict__ b2,
    f4* __restrict__ out,
    float* seg_sum, int* counts, int* cum_done, int* gate_ready, float* gate)
{
    const int tid = threadIdx.x;
    const int blk = blockIdx.x;

    if (blk < NMLP) {
        // ================= MLP role =================
        const int s = blk;
        __shared__ float c[H];
        __shared__ float hd[H];

        // round in which segment s ends (bid sorted, read-only input)
        int re = ROUNDS - 1;
        for (int r = 0; r < ROUNDS - 1; ++r) {
            if (bid[(r + 1) * RROWS] > s) { re = r; break; }
        }
        if (tid == 0) {
            while (ipoll(&cum_done[re]) < NSTRM) __builtin_amdgcn_s_sleep(32);
        }
        __syncthreads();

        // coherent reads of the accumulated sums (RMW add-0)
        const float cnt = fmaxf((float)ipoll(&counts[s]), 1.0f);
        c[tid]       = fread_rmw(&seg_sum[s * H + tid])       / cnt;
        c[tid + 256] = fread_rmw(&seg_sum[s * H + tid + 256]) / cnt;
        __syncthreads();

        const int w = tid >> 6, l = tid & 63;
        for (int jb = 0; jb < H / 4; ++jb) {
            const int j = jb * 4 + w;
            const float* wr = W1 + (size_t)j * H;
            float acc = 0.f;
            #pragma unroll
            for (int m = 0; m < H / 64; ++m) acc += c[m * 64 + l] * wr[m * 64 + l];
            #pragma unroll
            for (int off = 32; off > 0; off >>= 1) acc += __shfl_xor(acc, off, 64);
            if (l == 0) hd[j] = fmaxf(acc + b1[j], 0.f);
        }
        __syncthreads();
        for (int jb = 0; jb < H / 4; ++jb) {
            const int j = jb * 4 + w;
            const float* wr = W2 + (size_t)j * H;
            float acc = 0.f;
            #pragma unroll
            for (int m = 0; m < H / 64; ++m) acc += hd[m * 64 + l] * wr[m * 64 + l];
            #pragma unroll
            for (int off = 32; off > 0; off >>= 1) acc += __shfl_xor(acc, off, 64);
            if (l == 0) atomicExch(&gate[s * H + j],
                                   1.0f / (1.0f + expf(-(acc + b2[j]))));  // RMW write
        }
        __syncthreads();   // drains vmcnt: all gate exchs performed at coherence point
        if (tid == 0) ibump(&gate_ready[s], 1);
        return;
    }

    // ================= streaming role =================
    const int b = blk - NMLP;       // 0..511
    const int g = tid >> 7;         // row-parity group 0..1
    const int q = tid & 127;        // float4 column

    __shared__ int sbid[CROWS];
    __shared__ int gbid[CROWS];
    __shared__ f4  sred[2][QV];
    __shared__ u64 lg[2][H / 2];    // up to 2 gate rows, pulled via coherent RMW

    auto gate_phase = [&](int pr) {
        const int base = (pr * NSTRM + b) * CROWS;
        if (tid < CROWS) gbid[tid] = bid[base + tid];
        __syncthreads();
        const int s0 = gbid[0], s1 = gbid[CROWS - 1];
        if (tid == 0) {
            for (int s = s0; s <= s1; ++s)
                while (ipoll(&gate_ready[s]) == 0) __builtin_amdgcn_s_sleep(16);
        }
        __syncthreads();

        const f4* p = hv  + (size_t)(base + g) * QV + q;
        f4*       o = out + (size_t)(base + g) * QV + q;

        if (s1 - s0 <= 1) {
            // common path: 1-2 segments; pull gate row(s) via RMW -> LDS
            lg[0][tid] = uread_rmw((u64*)(gate + (size_t)s0 * H) + tid);
            if (s1 != s0)
                lg[1][tid] = uread_rmw((u64*)(gate + (size_t)s1 * H) + tid);
            __syncthreads();
            const f4 g0 = ((const f4*)lg[0])[q];
            const f4 g1 = (s1 != s0) ? ((const f4*)lg[1])[q] : g0;
            #pragma unroll 4
            for (int i = 0; i < 32; ++i) {
                const int row = g + 2 * i;
                const f4 gv = (gbid[row] == s0) ? g0 : g1;
                const f4 v = p[(size_t)(2 * i) * QV];
                ntstore4(o + (size_t)(2 * i) * QV, v * gv);
            }
            __syncthreads();   // lg reused next phase
        } else {
            // rare path: >=3 segments in one 64-row chunk
            int cur = gbid[g];
            u64* gp = (u64*)(gate + (size_t)cur * H) + 2 * q;
            union { u64 u[2]; f4 v; } cv;
            cv.u[0] = uread_rmw(gp); cv.u[1] = uread_rmw(gp + 1);
            for (int i = 0; i < 32; ++i) {
                const int row = g + 2 * i;
                const int s = gbid[row];
                if (s != cur) {
                    cur = s;
                    gp = (u64*)(gate + (size_t)cur * H) + 2 * q;
                    cv.u[0] = uread_rmw(gp); cv.u[1] = uread_rmw(gp + 1);
                }
                const f4 v = p[(size_t)(2 * i) * QV];
                ntstore4(o + (size_t)(2 * i) * QV, v * cv.v);
            }
            __syncthreads();
        }
    };

    for (int r = 0; r < ROUNDS; ++r) {
        // ---- sum chunk (r, b) ----
        const int base = (r * NSTRM + b) * CROWS;
        if (tid < CROWS) sbid[tid] = bid[base + tid];
        __syncthreads();

        const f4* p = hv + (size_t)(base + g) * QV + q;
        if (sbid[0] == sbid[CROWS - 1]) {
            // fast path: single-segment chunk, 4 independent accumulators
            f4 a0 = (f4)(0.f), a1 = (f4)(0.f), a2 = (f4)(0.f), a3 = (f4)(0.f);
            #pragma unroll
            for (int i = 0; i < 8; ++i) {
                a0 += p[(size_t)(8 * i + 0) * QV];
                a1 += p[(size_t)(8 * i + 2) * QV];
                a2 += p[(size_t)(8 * i + 4) * QV];
                a3 += p[(size_t)(8 * i + 6) * QV];
            }
            sred[g][q] = (a0 + a1) + (a2 + a3);
            __syncthreads();
            if (g == 0) {
                const int s0 = sbid[0];
                const f4 t = sred[0][q] + sred[1][q];
                float* dst = seg_sum + (size_t)s0 * H + q * 4;
                atomicAdd(dst + 0, t[0]); atomicAdd(dst + 1, t[1]);
                atomicAdd(dst + 2, t[2]); atomicAdd(dst + 3, t[3]);
                if (q == 0) atomicAdd(&counts[s0], CROWS);
            }
        } else {
            // slow path: chunk crosses segment boundary
            f4 acc = (f4)(0.f);
            int cur = sbid[g], cnt = 0;
            for (int i = 0; i < 32; ++i) {
                const int row = g + 2 * i;
                const f4 v = p[(size_t)(2 * i) * QV];
                const int s = sbid[row];
                if (s != cur) {
                    float* dst = seg_sum + (size_t)cur * H + q * 4;
                    atomicAdd(dst + 0, acc[0]); atomicAdd(dst + 1, acc[1]);
                    atomicAdd(dst + 2, acc[2]); atomicAdd(dst + 3, acc[3]);
                    if (q == 0) atomicAdd(&counts[cur], cnt);
                    acc = (f4)(0.f); cnt = 0; cur = s;
                }
                acc += v; ++cnt;
            }
            float* dst = seg_sum + (size_t)cur * H + q * 4;
            atomicAdd(dst + 0, acc[0]); atomicAdd(dst + 1, acc[1]);
            atomicAdd(dst + 2, acc[2]); atomicAdd(dst + 3, acc[3]);
            if (q == 0) atomicAdd(&counts[cur], cnt);
        }
        __syncthreads();   // all waves' seg_sum RMWs acked before the bump
        if (tid == 0) ibump(&cum_done[r], 1);

        // ---- gate chunk (r-1, b) while its h_V lines are L3-resident ----
        if (r >= 1) gate_phase(r - 1);
    }
    gate_phase(ROUNDS - 1);
}

extern "C" void kernel_launch(void* const* d_in, const int* in_sizes, int n_in,
                              void* d_out, int out_size, void* d_ws, size_t ws_size,
                              hipStream_t stream)
{
    const float* h_V      = (const float*)d_in[0];
    const int*   batch_id = (const int*)d_in[1];
    const float* W1       = (const float*)d_in[2];
    const float* b1       = (const float*)d_in[3];
    const float* W2       = (const float*)d_in[4];
    const float* b2       = (const float*)d_in[5];

    char*  ws         = (char*)d_ws;
    float* seg_sum    = (float*)ws;                 // 131072 B
    int*   counts     = (int*)(ws + 131072);        // 256 B
    int*   cum_done   = (int*)(ws + 131328);        // 64 B
    int*   gate_ready = (int*)(ws + 131392);        // 256 B
    float* gate       = (float*)(ws + 131648);      // 131072 B (always fully
                                                    // rewritten before flagged)

    hipMemsetAsync(d_ws, 0, 131648, stream);

    fused<<<NBLK, TPB, 0, stream>>>(
        (const f4*)h_V, batch_id, W1, b1, W2, b2,
        (f4*)d_out, seg_sum, counts, cum_done, gate_ready, gate);
}

// Round 7
// 1578.732 us; speedup vs baseline: 18.6181x; 1.0387x over previous
//
#include <hip/hip_runtime.h>

#define NTOT   262144
#define H      512
#define NSEG   64
#define TPB    256
#define NSTRM  512                      // blocks per round-kernel
#define CROWS  64                       // rows per block-chunk
#define ROUNDS 8                        // 32768 rows = 64 MiB per round
#define QV     (H / 4)                  // 128 float4 per row
#define RROWS  (NSTRM * CROWS)

typedef float f4 __attribute__((ext_vector_type(4)));

__device__ __forceinline__ void ntstore4(f4* p, f4 v) {
    __builtin_nontemporal_store(v, p);
}

// ---------------------------------------------------------------------------
// k_sum(round): accumulate segment sums/counts for one 64 MiB round.
// Plain loads (fill L3 for the matching k_gate 2 launches later).
// atomicAdd flush once per chunk (proven-fast primitive, R2/R6).
// ---------------------------------------------------------------------------
__global__ __launch_bounds__(TPB) void k_sum(
    const f4* __restrict__ hv, const int* __restrict__ bid,
    float* __restrict__ seg_sum, int* __restrict__ counts, int round)
{
    __shared__ int sbid[CROWS];
    __shared__ f4  sred[2][QV];
    const int base = (round * NSTRM + blockIdx.x) * CROWS;
    const int tid  = threadIdx.x;
    if (tid < CROWS) sbid[tid] = bid[base + tid];
    __syncthreads();

    const int g = tid >> 7;      // row-parity group 0..1
    const int q = tid & 127;     // float4 column
    const f4* p = hv + (size_t)(base + g) * QV + q;

    if (sbid[0] == sbid[CROWS - 1]) {
        // fast path: single-segment chunk, 4 independent load streams
        f4 a0 = (f4)(0.f), a1 = (f4)(0.f), a2 = (f4)(0.f), a3 = (f4)(0.f);
        #pragma unroll
        for (int i = 0; i < 8; ++i) {
            a0 += p[(size_t)(8 * i + 0) * QV];
            a1 += p[(size_t)(8 * i + 2) * QV];
            a2 += p[(size_t)(8 * i + 4) * QV];
            a3 += p[(size_t)(8 * i + 6) * QV];
        }
        sred[g][q] = (a0 + a1) + (a2 + a3);
        __syncthreads();
        if (g == 0) {
            const int s0 = sbid[0];
            const f4 t = sred[0][q] + sred[1][q];
            float* dst = seg_sum + (size_t)s0 * H + q * 4;
            atomicAdd(dst + 0, t[0]); atomicAdd(dst + 1, t[1]);
            atomicAdd(dst + 2, t[2]); atomicAdd(dst + 3, t[3]);
            if (q == 0) atomicAdd(&counts[s0], CROWS);
        }
    } else {
        // slow path: chunk crosses segment boundary (<=63 chunks grid-wide)
        f4 acc = (f4)(0.f);
        int cur = sbid[g], cnt = 0;
        for (int i = 0; i < 32; ++i) {
            const int row = g + 2 * i;
            const f4 v = p[(size_t)(2 * i) * QV];
            const int s = sbid[row];
            if (s != cur) {
                float* dst = seg_sum + (size_t)cur * H + q * 4;
                atomicAdd(dst + 0, acc[0]); atomicAdd(dst + 1, acc[1]);
                atomicAdd(dst + 2, acc[2]); atomicAdd(dst + 3, acc[3]);
                if (q == 0) atomicAdd(&counts[cur], cnt);
                acc = (f4)(0.f); cnt = 0; cur = s;
            }
            acc += v; ++cnt;
        }
        float* dst = seg_sum + (size_t)cur * H + q * 4;
        atomicAdd(dst + 0, acc[0]); atomicAdd(dst + 1, acc[1]);
        atomicAdd(dst + 2, acc[2]); atomicAdd(dst + 3, acc[3]);
        if (q == 0) atomicAdd(&counts[cur], cnt);
    }
}

// ---------------------------------------------------------------------------
// k_gate(round): launched after k_sum(round+1) in stream order, so every
// segment overlapping this round (length <= ~4350 << 32768) is fully summed,
// and coherence is given by the kernel-dispatch acquire. Each block computes
// the gates for its own 1-2 segments (redundant across blocks, deterministic),
// then streams: out = h_V * gate. h_V lines are <=192 MiB old -> L3 hits.
// Dual-segment dot product shares each W-row load.
// ---------------------------------------------------------------------------
__global__ __launch_bounds__(TPB) void k_gate(
    const f4* __restrict__ hv, const int* __restrict__ bid,
    const float* __restrict__ seg_sum, const int* __restrict__ counts,
    const float* __restrict__ W1, const float* __restrict__ b1,
    const float* __restrict__ W2, const float* __restrict__ b2,
    f4* __restrict__ out, int round)
{
    __shared__ int   gbid[CROWS];
    __shared__ float c2[2][H];
    __shared__ float hd2[2][H];
    __shared__ float gal[4][H];
    const int base = (round * NSTRM + blockIdx.x) * CROWS;
    const int tid  = threadIdx.x;
    if (tid < CROWS) gbid[tid] = bid[base + tid];
    __syncthreads();

    const int s0 = gbid[0];
    int ns = gbid[CROWS - 1] - s0 + 1;
    if (ns > 4) ns = 4;                  // impossible for this input; safety
    const int w = tid >> 6, l = tid & 63;

    // process segments in pairs, sharing weight loads
    for (int t = 0; t < ns; t += 2) {
        const int sA = s0 + t;
        const int sB = (t + 1 < ns) ? sA + 1 : sA;   // dup if odd count
        const float cA = fmaxf((float)counts[sA], 1.f);
        const float cB = fmaxf((float)counts[sB], 1.f);
        c2[0][tid]       = seg_sum[(size_t)sA * H + tid]       / cA;
        c2[0][tid + 256] = seg_sum[(size_t)sA * H + tid + 256] / cA;
        c2[1][tid]       = seg_sum[(size_t)sB * H + tid]       / cB;
        c2[1][tid + 256] = seg_sum[(size_t)sB * H + tid + 256] / cB;
        __syncthreads();

        for (int jb = 0; jb < H / 4; ++jb) {
            const int j = jb * 4 + w;
            const float* wr = W1 + (size_t)j * H;
            float aA = 0.f, aB = 0.f;
            #pragma unroll
            for (int m = 0; m < 8; ++m) {
                const float wv = wr[m * 64 + l];
                aA += c2[0][m * 64 + l] * wv;
                aB += c2[1][m * 64 + l] * wv;
            }
            #pragma unroll
            for (int off = 32; off > 0; off >>= 1) {
                aA += __shfl_xor(aA, off, 64);
                aB += __shfl_xor(aB, off, 64);
            }
            if (l == 0) {
                hd2[0][j] = fmaxf(aA + b1[j], 0.f);
                hd2[1][j] = fmaxf(aB + b1[j], 0.f);
            }
        }
        __syncthreads();

        for (int jb = 0; jb < H / 4; ++jb) {
            const int j = jb * 4 + w;
            const float* wr = W2 + (size_t)j * H;
            float aA = 0.f, aB = 0.f;
            #pragma unroll
            for (int m = 0; m < 8; ++m) {
                const float wv = wr[m * 64 + l];
                aA += hd2[0][m * 64 + l] * wv;
                aB += hd2[1][m * 64 + l] * wv;
            }
            #pragma unroll
            for (int off = 32; off > 0; off >>= 1) {
                aA += __shfl_xor(aA, off, 64);
                aB += __shfl_xor(aB, off, 64);
            }
            if (l == 0) {
                gal[t][j] = 1.f / (1.f + expf(-(aA + b2[j])));
                if (t + 1 < ns) gal[t + 1][j] = 1.f / (1.f + expf(-(aB + b2[j])));
            }
        }
        __syncthreads();
    }

    // streaming gate: plain loads (L3-resident), NT stores (write-once)
    const int g = tid >> 7, q = tid & 127;
    const f4* p = hv  + (size_t)(base + g) * QV + q;
    f4*       o = out + (size_t)(base + g) * QV + q;
    #pragma unroll 4
    for (int i = 0; i < 32; ++i) {
        const int row = g + 2 * i;
        int k = gbid[row] - s0; if (k > 3) k = 3;
        const f4 gv = ((const f4*)gal[k])[q];
        const f4 v = p[(size_t)(2 * i) * QV];
        ntstore4(o + (size_t)(2 * i) * QV, v * gv);
    }
}

extern "C" void kernel_launch(void* const* d_in, const int* in_sizes, int n_in,
                              void* d_out, int out_size, void* d_ws, size_t ws_size,
                              hipStream_t stream)
{
    const float* h_V      = (const float*)d_in[0];
    const int*   batch_id = (const int*)d_in[1];
    const float* W1       = (const float*)d_in[2];
    const float* b1       = (const float*)d_in[3];
    const float* W2       = (const float*)d_in[4];
    const float* b2       = (const float*)d_in[5];

    char*  ws      = (char*)d_ws;
    float* seg_sum = (float*)ws;              // 131072 B
    int*   counts  = (int*)(ws + 131072);     // 256 B

    hipMemsetAsync(d_ws, 0, 131328, stream);

    const f4* hv = (const f4*)h_V;
    f4* out = (f4*)d_out;

    // S0, S1, G0, S2, G1, ..., S7, G6, G7  (G(r) after S(r+1))
    k_sum<<<NSTRM, TPB, 0, stream>>>(hv, batch_id, seg_sum, counts, 0);
    for (int r = 1; r < ROUNDS; ++r) {
        k_sum<<<NSTRM, TPB, 0, stream>>>(hv, batch_id, seg_sum, counts, r);
        k_gate<<<NSTRM, TPB, 0, stream>>>(hv, batch_id, seg_sum, counts,
                                          W1, b1, W2, b2, out, r - 1);
    }
    k_gate<<<NSTRM, TPB, 0, stream>>>(hv, batch_id, seg_sum, counts,
                                      W1, b1, W2, b2, out, ROUNDS - 1);
}

// Round 8
// 629.500 us; speedup vs baseline: 46.6925x; 2.5079x over previous
//
#include <hip/hip_runtime.h>

#define NTOT   262144
#define H      512
#define NSEG   64
#define TPB    256
#define CHUNK  128                      // rows per block
#define NBLK   (NTOT / CHUNK)           // 2048 blocks
#define QV     (H / 4)                  // 128 float4 per row

typedef float f4 __attribute__((ext_vector_type(4)));

// ---------------------------------------------------------------------------
// k1: segment sums + counts. 2048 blocks x 256 thr (32 waves/CU). Each block
// owns 128 contiguous rows; 2 row-groups x 128 lanes. Fast path (>=97% of
// blocks, single segment): 8 independent accumulator streams -> LDS reduce ->
// one 512-float atomic flush. Slow path: register run-length + flush per
// boundary (proven R2/R6/R7).
// ---------------------------------------------------------------------------
__global__ __launch_bounds__(TPB, 8) void k_sum(
    const f4* __restrict__ hv, const int* __restrict__ bid,
    float* __restrict__ seg_sum, int* __restrict__ counts)
{
    __shared__ int sbid[CHUNK];
    __shared__ f4  sred[2][QV];
    const int base = blockIdx.x * CHUNK;
    const int tid  = threadIdx.x;
    if (tid < CHUNK) sbid[tid] = bid[base + tid];
    __syncthreads();

    const int g = tid >> 7;      // row-parity group 0..1
    const int q = tid & 127;     // float4 column
    const f4* p = hv + (size_t)(base + g) * QV + q;

    if (sbid[0] == sbid[CHUNK - 1]) {
        // ---- fast path: 8 independent load/accumulate streams ----
        f4 a[8];
        #pragma unroll
        for (int k = 0; k < 8; ++k) a[k] = (f4)(0.f);
        for (int ib = 0; ib < 8; ++ib) {
            #pragma unroll
            for (int k = 0; k < 8; ++k)
                a[k] += p[(size_t)(2 * (ib * 8 + k)) * QV];
        }
        const f4 t = ((a[0] + a[1]) + (a[2] + a[3])) +
                     ((a[4] + a[5]) + (a[6] + a[7]));
        sred[g][q] = t;
        __syncthreads();
        if (g == 0) {
            const int s0 = sbid[0];
            const f4 u = sred[0][q] + sred[1][q];
            float* dst = seg_sum + (size_t)s0 * H + q * 4;
            atomicAdd(dst + 0, u[0]); atomicAdd(dst + 1, u[1]);
            atomicAdd(dst + 2, u[2]); atomicAdd(dst + 3, u[3]);
            if (q == 0) atomicAdd(&counts[s0], CHUNK);
        }
    } else {
        // ---- slow path: block crosses a segment boundary ----
        f4 acc = (f4)(0.f);
        int cur = sbid[g], cnt = 0;
        for (int i = 0; i < 64; ++i) {
            const int row = g + 2 * i;
            const f4 v = p[(size_t)(2 * i) * QV];
            const int s = sbid[row];
            if (s != cur) {
                float* dst = seg_sum + (size_t)cur * H + q * 4;
                atomicAdd(dst + 0, acc[0]); atomicAdd(dst + 1, acc[1]);
                atomicAdd(dst + 2, acc[2]); atomicAdd(dst + 3, acc[3]);
                if (q == 0) atomicAdd(&counts[cur], cnt);
                acc = (f4)(0.f); cnt = 0; cur = s;
            }
            acc += v; ++cnt;
        }
        float* dst = seg_sum + (size_t)cur * H + q * 4;
        atomicAdd(dst + 0, acc[0]); atomicAdd(dst + 1, acc[1]);
        atomicAdd(dst + 2, acc[2]); atomicAdd(dst + 3, acc[3]);
        if (q == 0) atomicAdd(&counts[cur], cnt);
    }
}

// ---------------------------------------------------------------------------
// k_gate: fused (redundant per-block MLP) + branch-free gated stream.
// Kernel boundary provides coherence for seg_sum/counts (proven R2/R7).
// Each block computes gates for its own 1-2 segments (pair-shared W loads,
// proven correct in R7), builds an LDS gate table + per-row index table,
// then streams 128 rows: out = h_V * gal[idx8[row]]. No data-dependent
// branches in the stream; 8 loads in flight; plain stores (m13 pattern).
// ---------------------------------------------------------------------------
__global__ __launch_bounds__(TPB, 8) void k_gate(
    const f4* __restrict__ hv, const int* __restrict__ bid,
    const float* __restrict__ seg_sum, const int* __restrict__ counts,
    const float* __restrict__ W1, const float* __restrict__ b1,
    const float* __restrict__ W2, const float* __restrict__ b2,
    f4* __restrict__ out)
{
    __shared__ int   gbid[CHUNK];
    __shared__ int   idx8[CHUNK];
    __shared__ float c2[2][H];
    __shared__ float hd2[2][H];
    __shared__ float gal[4][H];
    const int base = blockIdx.x * CHUNK;
    const int tid  = threadIdx.x;
    if (tid < CHUNK) gbid[tid] = bid[base + tid];
    __syncthreads();

    const int s0 = gbid[0];
    int ns = gbid[CHUNK - 1] - s0 + 1;
    if (ns > 4) ns = 4;                  // impossible here (min seg >> 128); safety
    if (tid < CHUNK) {
        int k = gbid[tid] - s0; if (k > 3) k = 3;
        idx8[tid] = k;
    }
    const int w = tid >> 6, l = tid & 63;

    // segments in pairs, sharing each W-row load
    for (int t = 0; t < ns; t += 2) {
        const int sA = s0 + t;
        const int sB = (t + 1 < ns) ? sA + 1 : sA;
        const float cA = fmaxf((float)counts[sA], 1.f);
        const float cB = fmaxf((float)counts[sB], 1.f);
        c2[0][tid]       = seg_sum[(size_t)sA * H + tid]       / cA;
        c2[0][tid + 256] = seg_sum[(size_t)sA * H + tid + 256] / cA;
        c2[1][tid]       = seg_sum[(size_t)sB * H + tid]       / cB;
        c2[1][tid + 256] = seg_sum[(size_t)sB * H + tid + 256] / cB;
        __syncthreads();

        for (int jb = 0; jb < H / 4; ++jb) {
            const int j = jb * 4 + w;
            const float* wr = W1 + (size_t)j * H;
            float aA = 0.f, aB = 0.f;
            #pragma unroll
            for (int m = 0; m < 8; ++m) {
                const float wv = wr[m * 64 + l];
                aA += c2[0][m * 64 + l] * wv;
                aB += c2[1][m * 64 + l] * wv;
            }
            #pragma unroll
            for (int off = 32; off > 0; off >>= 1) {
                aA += __shfl_xor(aA, off, 64);
                aB += __shfl_xor(aB, off, 64);
            }
            if (l == 0) {
                hd2[0][j] = fmaxf(aA + b1[j], 0.f);
                hd2[1][j] = fmaxf(aB + b1[j], 0.f);
            }
        }
        __syncthreads();

        for (int jb = 0; jb < H / 4; ++jb) {
            const int j = jb * 4 + w;
            const float* wr = W2 + (size_t)j * H;
            float aA = 0.f, aB = 0.f;
            #pragma unroll
            for (int m = 0; m < 8; ++m) {
                const float wv = wr[m * 64 + l];
                aA += hd2[0][m * 64 + l] * wv;
                aB += hd2[1][m * 64 + l] * wv;
            }
            #pragma unroll
            for (int off = 32; off > 0; off >>= 1) {
                aA += __shfl_xor(aA, off, 64);
                aB += __shfl_xor(aB, off, 64);
            }
            if (l == 0) {
                gal[t][j] = 1.f / (1.f + expf(-(aA + b2[j])));
                if (t + 1 < ns) gal[t + 1][j] = 1.f / (1.f + expf(-(aB + b2[j])));
            }
        }
        __syncthreads();
    }

    // ---- branch-free gated stream: 128 rows, 8 loads in flight ----
    const int g = tid >> 7, q = tid & 127;
    const f4* p = hv  + (size_t)(base + g) * QV + q;
    f4*       o = out + (size_t)(base + g) * QV + q;
    for (int ib = 0; ib < 8; ++ib) {
        f4 v[8];
        #pragma unroll
        for (int k = 0; k < 8; ++k)
            v[k] = p[(size_t)(2 * (ib * 8 + k)) * QV];
        #pragma unroll
        for (int k = 0; k < 8; ++k) {
            const int row = g + 2 * (ib * 8 + k);
            const f4 gv = ((const f4*)gal[idx8[row]])[q];
            o[(size_t)(2 * (ib * 8 + k)) * QV] = v[k] * gv;
        }
    }
}

extern "C" void kernel_launch(void* const* d_in, const int* in_sizes, int n_in,
                              void* d_out, int out_size, void* d_ws, size_t ws_size,
                              hipStream_t stream)
{
    const float* h_V      = (const float*)d_in[0];
    const int*   batch_id = (const int*)d_in[1];
    const float* W1       = (const float*)d_in[2];
    const float* b1       = (const float*)d_in[3];
    const float* W2       = (const float*)d_in[4];
    const float* b2       = (const float*)d_in[5];

    char*  ws      = (char*)d_ws;
    float* seg_sum = (float*)ws;              // 131072 B
    int*   counts  = (int*)(ws + 131072);     // 256 B

    hipMemsetAsync(d_ws, 0, 131328, stream);

    k_sum<<<NBLK, TPB, 0, stream>>>(
        (const f4*)h_V, batch_id, seg_sum, counts);

    k_gate<<<NBLK, TPB, 0, stream>>>(
        (const f4*)h_V, batch_id, seg_sum, counts,
        W1, b1, W2, b2, (f4*)d_out);
}

// Round 9
// 432.972 us; speedup vs baseline: 67.8864x; 1.4539x over previous
//
#include <hip/hip_runtime.h>

#define NTOT   262144
#define H      512
#define NSEG   64
#define TPB    256
#define CHUNK  128                      // rows per block
#define NBLK   (NTOT / CHUNK)           // 2048 blocks
#define QV     (H / 4)                  // 128 float4 per row

typedef float f4 __attribute__((ext_vector_type(4)));

// ---------------------------------------------------------------------------
// k_sum: segment sums + counts. 2048 blocks x 256 thr. Each block owns 128
// contiguous rows; 2 row-groups x 128 lanes. Fast path (single-segment
// block, >=97%): 8 independent accumulator streams -> LDS reduce -> one
// 512-float atomic flush. Plain loads (fills L3; k_stream re-reads hit —
// verified R8: k_gate FETCH was 300 MB of 532 MB).
// ---------------------------------------------------------------------------
__global__ __launch_bounds__(TPB, 8) void k_sum(
    const f4* __restrict__ hv, const int* __restrict__ bid,
    float* __restrict__ seg_sum, int* __restrict__ counts)
{
    __shared__ int sbid[CHUNK];
    __shared__ f4  sred[2][QV];
    const int base = blockIdx.x * CHUNK;
    const int tid  = threadIdx.x;
    if (tid < CHUNK) sbid[tid] = bid[base + tid];
    __syncthreads();

    const int g = tid >> 7;      // row-parity group 0..1
    const int q = tid & 127;     // float4 column
    const f4* p = hv + (size_t)(base + g) * QV + q;

    if (sbid[0] == sbid[CHUNK - 1]) {
        // ---- fast path: 8 independent load/accumulate streams ----
        f4 a[8];
        #pragma unroll
        for (int k = 0; k < 8; ++k) a[k] = (f4)(0.f);
        for (int ib = 0; ib < 8; ++ib) {
            #pragma unroll
            for (int k = 0; k < 8; ++k)
                a[k] += p[(size_t)(2 * (ib * 8 + k)) * QV];
        }
        const f4 t = ((a[0] + a[1]) + (a[2] + a[3])) +
                     ((a[4] + a[5]) + (a[6] + a[7]));
        sred[g][q] = t;
        __syncthreads();
        if (g == 0) {
            const int s0 = sbid[0];
            const f4 u = sred[0][q] + sred[1][q];
            float* dst = seg_sum + (size_t)s0 * H + q * 4;
            atomicAdd(dst + 0, u[0]); atomicAdd(dst + 1, u[1]);
            atomicAdd(dst + 2, u[2]); atomicAdd(dst + 3, u[3]);
            if (q == 0) atomicAdd(&counts[s0], CHUNK);
        }
    } else {
        // ---- slow path: block crosses a segment boundary ----
        f4 acc = (f4)(0.f);
        int cur = sbid[g], cnt = 0;
        for (int i = 0; i < 64; ++i) {
            const int row = g + 2 * i;
            const f4 v = p[(size_t)(2 * i) * QV];
            const int s = sbid[row];
            if (s != cur) {
                float* dst = seg_sum + (size_t)cur * H + q * 4;
                atomicAdd(dst + 0, acc[0]); atomicAdd(dst + 1, acc[1]);
                atomicAdd(dst + 2, acc[2]); atomicAdd(dst + 3, acc[3]);
                if (q == 0) atomicAdd(&counts[cur], cnt);
                acc = (f4)(0.f); cnt = 0; cur = s;
            }
            acc += v; ++cnt;
        }
        float* dst = seg_sum + (size_t)cur * H + q * 4;
        atomicAdd(dst + 0, acc[0]); atomicAdd(dst + 1, acc[1]);
        atomicAdd(dst + 2, acc[2]); atomicAdd(dst + 3, acc[3]);
        if (q == 0) atomicAdd(&counts[cur], cnt);
    }
}

// ---------------------------------------------------------------------------
// k_mlp: per-segment gated MLP, computed ONCE (R8 lesson: duplicating this
// per streaming block cost 4 GB of weight traffic). 64 blocks x 512 thr,
// wave-per-output dot products, shfl butterfly reduce. ~2 MB weight reads.
// ---------------------------------------------------------------------------
__global__ __launch_bounds__(512) void k_mlp(
    const float* __restrict__ seg_sum, const int* __restrict__ counts,
    const float* __restrict__ W1, const float* __restrict__ b1,
    const float* __restrict__ W2, const float* __restrict__ b2,
    float* __restrict__ gate)
{
    __shared__ float c[H];
    __shared__ float hd[H];
    const int s   = blockIdx.x;
    const int tid = threadIdx.x;

    const float cntf = fmaxf((float)counts[s], 1.0f);
    c[tid] = seg_sum[s * H + tid] / cntf;
    __syncthreads();

    const int w = tid >> 6;   // wave 0..7
    const int l = tid & 63;   // lane 0..63

    for (int jb = 0; jb < H / 8; ++jb) {
        const int j = jb * 8 + w;
        const float* __restrict__ wr = W1 + (size_t)j * H;
        float acc = 0.f;
        #pragma unroll
        for (int m = 0; m < H / 64; ++m)
            acc += c[m * 64 + l] * wr[m * 64 + l];
        #pragma unroll
        for (int off = 32; off > 0; off >>= 1)
            acc += __shfl_xor(acc, off, 64);
        if (l == 0) hd[j] = fmaxf(acc + b1[j], 0.f);
    }
    __syncthreads();

    for (int jb = 0; jb < H / 8; ++jb) {
        const int j = jb * 8 + w;
        const float* __restrict__ wr = W2 + (size_t)j * H;
        float acc = 0.f;
        #pragma unroll
        for (int m = 0; m < H / 64; ++m)
            acc += hd[m * 64 + l] * wr[m * 64 + l];
        #pragma unroll
        for (int off = 32; off > 0; off >>= 1)
            acc += __shfl_xor(acc, off, 64);
        if (l == 0) gate[s * H + j] = 1.0f / (1.0f + expf(-(acc + b2[j])));
    }
}

// ---------------------------------------------------------------------------
// k_stream: out = h_V * gate[batch_id]. Per block: pull its 1-2 gate rows
// (4 KB, L3-resident) into LDS, build per-row index table, then branch-free
// stream of 128 rows with 8 loads in flight. Plain loads (h_V partially
// L3-resident from k_sum), plain stores.
// ---------------------------------------------------------------------------
__global__ __launch_bounds__(TPB, 8) void k_stream(
    const f4* __restrict__ hv, const int* __restrict__ bid,
    const float* __restrict__ gate, f4* __restrict__ out)
{
    __shared__ int   gbid[CHUNK];
    __shared__ int   idx8[CHUNK];
    __shared__ float gal[4][H];
    const int base = blockIdx.x * CHUNK;
    const int tid  = threadIdx.x;
    if (tid < CHUNK) gbid[tid] = bid[base + tid];
    __syncthreads();

    const int s0 = gbid[0];
    int ns = gbid[CHUNK - 1] - s0 + 1;
    if (ns > 4) ns = 4;                  // impossible here (min seg >> 512); safety
    if (tid < CHUNK) {
        int k = gbid[tid] - s0; if (k > 3) k = 3;
        idx8[tid] = k;
    }
    for (int t = 0; t < ns; ++t) {
        gal[t][tid]       = gate[(size_t)(s0 + t) * H + tid];
        gal[t][tid + 256] = gate[(size_t)(s0 + t) * H + tid + 256];
    }
    __syncthreads();

    const int g = tid >> 7, q = tid & 127;
    const f4* p = hv  + (size_t)(base + g) * QV + q;
    f4*       o = out + (size_t)(base + g) * QV + q;
    for (int ib = 0; ib < 8; ++ib) {
        f4 v[8];
        #pragma unroll
        for (int k = 0; k < 8; ++k)
            v[k] = p[(size_t)(2 * (ib * 8 + k)) * QV];
        #pragma unroll
        for (int k = 0; k < 8; ++k) {
            const int row = g + 2 * (ib * 8 + k);
            const f4 gv = ((const f4*)gal[idx8[row]])[q];
            o[(size_t)(2 * (ib * 8 + k)) * QV] = v[k] * gv;
        }
    }
}

extern "C" void kernel_launch(void* const* d_in, const int* in_sizes, int n_in,
                              void* d_out, int out_size, void* d_ws, size_t ws_size,
                              hipStream_t stream)
{
    const float* h_V      = (const float*)d_in[0];
    const int*   batch_id = (const int*)d_in[1];
    const float* W1       = (const float*)d_in[2];
    const float* b1       = (const float*)d_in[3];
    const float* W2       = (const float*)d_in[4];
    const float* b2       = (const float*)d_in[5];

    char*  ws      = (char*)d_ws;
    float* seg_sum = (float*)ws;                  // 131072 B
    int*   counts  = (int*)(ws + 131072);         // 256 B
    float* gate    = (float*)(ws + 131328);       // 131072 B

    hipMemsetAsync(d_ws, 0, 131328, stream);

    k_sum<<<NBLK, TPB, 0, stream>>>(
        (const f4*)h_V, batch_id, seg_sum, counts);

    k_mlp<<<NSEG, 512, 0, stream>>>(
        seg_sum, counts, W1, b1, W2, b2, gate);

    k_stream<<<NBLK, TPB, 0, stream>>>(
        (const f4*)h_V, batch_id, gate, (f4*)d_out);
}

// Round 10
// 421.520 us; speedup vs baseline: 69.7309x; 1.0272x over previous
//
#include <hip/hip_runtime.h>

#define NTOT   262144
#define H      512
#define NSEG   64
#define TPB    256
#define CHUNK  128                      // rows per block
#define NBLK   (NTOT / CHUNK)           // 2048 blocks
#define QV     (H / 4)                  // 128 float4 per row

typedef float f4 __attribute__((ext_vector_type(4)));

__device__ __forceinline__ void ntstore4(f4* p, f4 v) {
    __builtin_nontemporal_store(v, p);
}

// ---------------------------------------------------------------------------
// k_sum: segment sums + counts. 2048 blocks x 256 thr. Each block owns 128
// contiguous rows; 2 row-groups x 128 lanes. Fast path (single-segment
// block, >=97%): 8 independent accumulator streams -> LDS reduce -> one
// 512-float atomic flush. Plain loads (seeds L3; k_stream re-reads hit —
// verified R8: streaming kernel FETCH was 300 MB of 532 MB).
// ---------------------------------------------------------------------------
__global__ __launch_bounds__(TPB, 8) void k_sum(
    const f4* __restrict__ hv, const int* __restrict__ bid,
    float* __restrict__ seg_sum, int* __restrict__ counts)
{
    __shared__ int sbid[CHUNK];
    __shared__ f4  sred[2][QV];
    const int base = blockIdx.x * CHUNK;
    const int tid  = threadIdx.x;
    if (tid < CHUNK) sbid[tid] = bid[base + tid];
    __syncthreads();

    const int g = tid >> 7;      // row-parity group 0..1
    const int q = tid & 127;     // float4 column
    const f4* p = hv + (size_t)(base + g) * QV + q;

    if (sbid[0] == sbid[CHUNK - 1]) {
        // ---- fast path: 8 independent load/accumulate streams ----
        f4 a[8];
        #pragma unroll
        for (int k = 0; k < 8; ++k) a[k] = (f4)(0.f);
        for (int ib = 0; ib < 8; ++ib) {
            #pragma unroll
            for (int k = 0; k < 8; ++k)
                a[k] += p[(size_t)(2 * (ib * 8 + k)) * QV];
        }
        const f4 t = ((a[0] + a[1]) + (a[2] + a[3])) +
                     ((a[4] + a[5]) + (a[6] + a[7]));
        sred[g][q] = t;
        __syncthreads();
        if (g == 0) {
            const int s0 = sbid[0];
            const f4 u = sred[0][q] + sred[1][q];
            float* dst = seg_sum + (size_t)s0 * H + q * 4;
            atomicAdd(dst + 0, u[0]); atomicAdd(dst + 1, u[1]);
            atomicAdd(dst + 2, u[2]); atomicAdd(dst + 3, u[3]);
            if (q == 0) atomicAdd(&counts[s0], CHUNK);
        }
    } else {
        // ---- slow path: block crosses a segment boundary ----
        f4 acc = (f4)(0.f);
        int cur = sbid[g], cnt = 0;
        for (int i = 0; i < 64; ++i) {
            const int row = g + 2 * i;
            const f4 v = p[(size_t)(2 * i) * QV];
            const int s = sbid[row];
            if (s != cur) {
                float* dst = seg_sum + (size_t)cur * H + q * 4;
                atomicAdd(dst + 0, acc[0]); atomicAdd(dst + 1, acc[1]);
                atomicAdd(dst + 2, acc[2]); atomicAdd(dst + 3, acc[3]);
                if (q == 0) atomicAdd(&counts[cur], cnt);
                acc = (f4)(0.f); cnt = 0; cur = s;
            }
            acc += v; ++cnt;
        }
        float* dst = seg_sum + (size_t)cur * H + q * 4;
        atomicAdd(dst + 0, acc[0]); atomicAdd(dst + 1, acc[1]);
        atomicAdd(dst + 2, acc[2]); atomicAdd(dst + 3, acc[3]);
        if (q == 0) atomicAdd(&counts[cur], cnt);
    }
}

// ---------------------------------------------------------------------------
// k_mlp: per-segment gated MLP, computed ONCE (R8 lesson: per-block
// duplication cost 4 GB of weight traffic). 64 blocks x 512 thr.
// ---------------------------------------------------------------------------
__global__ __launch_bounds__(512) void k_mlp(
    const float* __restrict__ seg_sum, const int* __restrict__ counts,
    const float* __restrict__ W1, const float* __restrict__ b1,
    const float* __restrict__ W2, const float* __restrict__ b2,
    float* __restrict__ gate)
{
    __shared__ float c[H];
    __shared__ float hd[H];
    const int s   = blockIdx.x;
    const int tid = threadIdx.x;

    const float cntf = fmaxf((float)counts[s], 1.0f);
    c[tid] = seg_sum[s * H + tid] / cntf;
    __syncthreads();

    const int w = tid >> 6;   // wave 0..7
    const int l = tid & 63;   // lane 0..63

    for (int jb = 0; jb < H / 8; ++jb) {
        const int j = jb * 8 + w;
        const float* __restrict__ wr = W1 + (size_t)j * H;
        float acc = 0.f;
        #pragma unroll
        for (int m = 0; m < H / 64; ++m)
            acc += c[m * 64 + l] * wr[m * 64 + l];
        #pragma unroll
        for (int off = 32; off > 0; off >>= 1)
            acc += __shfl_xor(acc, off, 64);
        if (l == 0) hd[j] = fmaxf(acc + b1[j], 0.f);
    }
    __syncthreads();

    for (int jb = 0; jb < H / 8; ++jb) {
        const int j = jb * 8 + w;
        const float* __restrict__ wr = W2 + (size_t)j * H;
        float acc = 0.f;
        #pragma unroll
        for (int m = 0; m < H / 64; ++m)
            acc += hd[m * 64 + l] * wr[m * 64 + l];
        #pragma unroll
        for (int off = 32; off > 0; off >>= 1)
            acc += __shfl_xor(acc, off, 64);
        if (l == 0) gate[s * H + j] = 1.0f / (1.0f + expf(-(acc + b2[j])));
    }
}

// ---------------------------------------------------------------------------
// k_stream: out = h_V * gate[batch_id].
// Fast path (single-segment block, >=97%): gate f4 hoisted into ONE register
// (wave-uniform) -> steady-state loop is pure load/mul/store, zero LDS.
// NT stores: out is write-once; keep it out of L3 so the h_V lines seeded by
// k_sum survive until read (R8: plain stores still left 300 MB of misses).
// Slow path: LDS gate table + per-row index (branch-free).
// ---------------------------------------------------------------------------
__global__ __launch_bounds__(TPB, 8) void k_stream(
    const f4* __restrict__ hv, const int* __restrict__ bid,
    const float* __restrict__ gate, f4* __restrict__ out)
{
    __shared__ int   gbid[CHUNK];
    __shared__ int   idx8[CHUNK];
    __shared__ float gal[4][H];
    const int base = blockIdx.x * CHUNK;
    const int tid  = threadIdx.x;
    if (tid < CHUNK) gbid[tid] = bid[base + tid];
    __syncthreads();

    const int g = tid >> 7, q = tid & 127;
    const f4* p = hv  + (size_t)(base + g) * QV + q;
    f4*       o = out + (size_t)(base + g) * QV + q;

    if (gbid[0] == gbid[CHUNK - 1]) {
        // ---- fast path: one gate vector in a register, pure stream ----
        const f4 gv = *((const f4*)(gate + (size_t)gbid[0] * H) + q);
        for (int ib = 0; ib < 8; ++ib) {
            f4 v[8];
            #pragma unroll
            for (int k = 0; k < 8; ++k)
                v[k] = p[(size_t)(2 * (ib * 8 + k)) * QV];
            #pragma unroll
            for (int k = 0; k < 8; ++k)
                ntstore4(o + (size_t)(2 * (ib * 8 + k)) * QV, v[k] * gv);
        }
        return;
    }

    // ---- slow path: block crosses a segment boundary ----
    const int s0 = gbid[0];
    int ns = gbid[CHUNK - 1] - s0 + 1;
    if (ns > 4) ns = 4;                  // impossible here (min seg >> 512); safety
    if (tid < CHUNK) {
        int k = gbid[tid] - s0; if (k > 3) k = 3;
        idx8[tid] = k;
    }
    for (int t = 0; t < ns; ++t) {
        gal[t][tid]       = gate[(size_t)(s0 + t) * H + tid];
        gal[t][tid + 256] = gate[(size_t)(s0 + t) * H + tid + 256];
    }
    __syncthreads();

    for (int ib = 0; ib < 8; ++ib) {
        f4 v[8];
        #pragma unroll
        for (int k = 0; k < 8; ++k)
            v[k] = p[(size_t)(2 * (ib * 8 + k)) * QV];
        #pragma unroll
        for (int k = 0; k < 8; ++k) {
            const int row = g + 2 * (ib * 8 + k);
            const f4 gv = ((const f4*)gal[idx8[row]])[q];
            ntstore4(o + (size_t)(2 * (ib * 8 + k)) * QV, v[k] * gv);
        }
    }
}

extern "C" void kernel_launch(void* const* d_in, const int* in_sizes, int n_in,
                              void* d_out, int out_size, void* d_ws, size_t ws_size,
                              hipStream_t stream)
{
    const float* h_V      = (const float*)d_in[0];
    const int*   batch_id = (const int*)d_in[1];
    const float* W1       = (const float*)d_in[2];
    const float* b1       = (const float*)d_in[3];
    const float* W2       = (const float*)d_in[4];
    const float* b2       = (const float*)d_in[5];

    char*  ws      = (char*)d_ws;
    float* seg_sum = (float*)ws;                  // 131072 B
    int*   counts  = (int*)(ws + 131072);         // 256 B
    float* gate    = (float*)(ws + 131328);       // 131072 B

    hipMemsetAsync(d_ws, 0, 131328, stream);

    k_sum<<<NBLK, TPB, 0, stream>>>(
        (const f4*)h_V, batch_id, seg_sum, counts);

    k_mlp<<<NSEG, 512, 0, stream>>>(
        seg_sum, counts, W1, b1, W2, b2, gate);

    k_stream<<<NBLK, TPB, 0, stream>>>(
        (const f4*)h_V, batch_id, gate, (f4*)d_out);
}